// Round 8
// baseline (94.194 us; speedup 1.0000x reference)
//
#include <hip/hip_runtime.h>
#include <stdint.h>

// kNN: B=2, N=2048, D=16, K=16. Output (B,N,K,2) int32: [batch_idx, neighbor_idx].
//
// Bit-exact vs numpy f32 reference — ONLY via named intrinsics
// (__fmul_rn/__fadd_rn/__fsqrt_rn), opaque to -ffp-contract=fast and
// reassociation. (R5 failed with plain FP operators: contraction reordered
// near-tie ranks.) Pairwise tree n=16: r[j]=s[j]+s[j+8];
// ((r0+r1)+(r2+r3))+((r4+r5)+(r6+r7)). __fsqrt_rn == np.sqrt.
// key = (dist_bits<<32)|idx : monotone, ties -> lower index (stable top_k).
// Self (c==n, unique global min) masked pre-selection == [:, :, 1:] slice.
//
// Hard-won constraints (do not regress):
//  - R6: NO partial unrolls over key arrays -> dynamic index -> scratch
//    (VGPR=52, WRITE_SIZE=145 MB, 72 us). Key-array indices must be
//    compile-time constants; loops fully unrolled.
//  - R4: launch_bounds 2nd arg=4 caps VGPR at 128 -> AGPR shuffling
//    (VGPR_Count=36, VALUBusy up, no gain). Use (128, 2) = 256 budget.
//  - R7: 1 wave = 1 query -> only 4096 waves vs 8192 slots -> occupancy
//    capped at 50% (measured 29%), latency unhidden, 43.5 us plateau.
//
// R8 structure: 1 block = 1 query, 2 waves; wave w handles candidates
// [w*1024,(w+1)*1024) -> 16 keys/lane (32 VGPRs, pressure halved vs R7).
// 8192 waves = full device wave capacity. Per wave: 2 sorted runs of 8
// (Batcher), 16 pop rounds (2-head argmin + DPP wave-min validated R4 +
// winner-lane run shift), top-16 of the half -> LDS list. One barrier.
// Lanes 0..15 rank-merge the two sorted 16-lists (keys unique -> exact
// counting merge) and write int2 outputs.

#define NPTS 2048
#define DIMS 16
#define KK 16
#define THREADS 128            // 2 waves = 1 query per block
#define CPL 16                 // candidates per lane (1024 / 64)

__device__ __forceinline__ void ce(uint64_t& a, uint64_t& b) {
    uint64_t lo = (a < b) ? a : b;
    uint64_t hi = (a < b) ? b : a;
    a = lo; b = hi;
}

// 64-lane u64 min-reduce via DPP; result broadcast to all lanes via readlane.
// (bit-validated in R4: absmax=0)
__device__ __forceinline__ uint64_t wave_min_u64(uint64_t v) {
    uint32_t lo = (uint32_t)v;
    uint32_t hi = (uint32_t)(v >> 32);
#define DPP_STEP(CTRL, RMASK)                                                   \
    {                                                                           \
        uint32_t slo = (uint32_t)__builtin_amdgcn_update_dpp(                   \
            -1, (int)lo, (CTRL), (RMASK), 0xF, false);                          \
        uint32_t shi = (uint32_t)__builtin_amdgcn_update_dpp(                   \
            -1, (int)hi, (CTRL), (RMASK), 0xF, false);                          \
        bool lt = (shi < hi) || ((shi == hi) && (slo < lo));                    \
        lo = lt ? slo : lo;                                                     \
        hi = lt ? shi : hi;                                                     \
    }
    DPP_STEP(0x111, 0xF);  // row_shr:1
    DPP_STEP(0x112, 0xF);  // row_shr:2
    DPP_STEP(0x114, 0xF);  // row_shr:4
    DPP_STEP(0x118, 0xF);  // row_shr:8  -> lane 15/31/47/63 = row min
    DPP_STEP(0x142, 0xA);  // row_bcast:15 -> lane 31 = min(0..31), 63 = min(32..63)
    DPP_STEP(0x143, 0xC);  // row_bcast:31 -> lane 63 = global min
#undef DPP_STEP
    uint32_t glo = (uint32_t)__builtin_amdgcn_readlane((int)lo, 63);
    uint32_t ghi = (uint32_t)__builtin_amdgcn_readlane((int)hi, 63);
    return ((uint64_t)ghi << 32) | glo;
}

__global__ __launch_bounds__(THREADS, 2) void knn_kernel(
    const float* __restrict__ points, int* __restrict__ out)
{
    const int tid = threadIdx.x;
    const int wave = tid >> 6;
    const int lane = tid & 63;
    const int q = blockIdx.x;              // 1 block = 1 query
    const int b = q >> 11;                 // N = 2048
    const int n = q & (NPTS - 1);
    const float* bp = points + (size_t)b * NPTS * DIMS;

    __shared__ uint64_t lists[2][KK];      // two sorted top-16 lists, 256 B

    // ---- query -> registers (broadcast loads) ----
    float qp[DIMS];
    {
        const float4* qp4 = (const float4*)(bp + (size_t)n * DIMS);
#pragma unroll
        for (int v = 0; v < 4; ++v) {
            float4 t = qp4[v];
            qp[4 * v + 0] = t.x; qp[4 * v + 1] = t.y;
            qp[4 * v + 2] = t.z; qp[4 * v + 3] = t.w;
        }
    }

    // ---- distance phase: 16 candidates/lane, FULLY unrolled (constant
    //      k[] indices -> SROA -> registers; see header) ----
    uint64_t k[CPL];
#pragma unroll
    for (int j = 0; j < CPL; ++j) {
        const int c = (wave << 10) + lane + (j << 6);   // coalesced per wave
        const float4* cp4 = (const float4*)(bp + (size_t)c * DIMS);
        float s[DIMS];
#pragma unroll
        for (int v = 0; v < 4; ++v) {
            float4 t = cp4[v];
            float d0 = qp[4 * v + 0] - t.x;
            float d1 = qp[4 * v + 1] - t.y;
            float d2_ = qp[4 * v + 2] - t.z;
            float d3 = qp[4 * v + 3] - t.w;
            s[4 * v + 0] = __fmul_rn(d0, d0);
            s[4 * v + 1] = __fmul_rn(d1, d1);
            s[4 * v + 2] = __fmul_rn(d2_, d2_);
            s[4 * v + 3] = __fmul_rn(d3, d3);
        }
        float r0 = __fadd_rn(s[0], s[8]);
        float r1 = __fadd_rn(s[1], s[9]);
        float r2 = __fadd_rn(s[2], s[10]);
        float r3 = __fadd_rn(s[3], s[11]);
        float r4 = __fadd_rn(s[4], s[12]);
        float r5 = __fadd_rn(s[5], s[13]);
        float r6 = __fadd_rn(s[6], s[14]);
        float r7 = __fadd_rn(s[7], s[15]);
        float t0 = __fadd_rn(r0, r1);
        float t1 = __fadd_rn(r2, r3);
        float t2 = __fadd_rn(r4, r5);
        float t3 = __fadd_rn(r6, r7);
        float d2 = __fadd_rn(__fadd_rn(t0, t1), __fadd_rn(t2, t3));
        float dist = __fsqrt_rn(d2);
        uint64_t key = ((uint64_t)__float_as_uint(dist) << 32) | (uint32_t)c;
        k[j] = (c == n) ? ~0ull : key;     // drop self pre-selection
    }

    // ---- 2 sorted runs of 8 (Batcher odd-even merge, 19 CEs each) ----
#pragma unroll
    for (int r = 0; r < 2; ++r) {
        uint64_t* p = k + r * 8;           // constant after unroll
        ce(p[0], p[1]); ce(p[2], p[3]); ce(p[4], p[5]); ce(p[6], p[7]);
        ce(p[0], p[2]); ce(p[1], p[3]); ce(p[4], p[6]); ce(p[5], p[7]);
        ce(p[1], p[2]); ce(p[5], p[6]);
        ce(p[0], p[4]); ce(p[1], p[5]); ce(p[2], p[6]); ce(p[3], p[7]);
        ce(p[1], p[4]); ce(p[3], p[6]);
        ce(p[2], p[4]); ce(p[3], p[5]);
        ce(p[3], p[4]);
    }

    // ---- 16 pop rounds: this wave's sorted top-16 of its half -> LDS ----
    for (int r = 0; r < KK; ++r) {
        const bool a_min = k[0] < k[8];
        const uint64_t m = a_min ? k[0] : k[8];
        const uint64_t g = wave_min_u64(m);
        if (m == g) {                      // unique winner lane (keys unique)
            lists[wave][r] = g;
            if (a_min) {
#pragma unroll
                for (int j = 0; j < 7; ++j) k[j] = k[j + 1];
                k[7] = ~0ull;
            } else {
#pragma unroll
                for (int j = 8; j < 15; ++j) k[j] = k[j + 1];
                k[15] = ~0ull;
            }
        }
    }
    __syncthreads();

    // ---- rank-merge the two sorted 16-lists; write ranks 0..15 ----
    if (lane < KK) {
        const uint64_t mine = lists[wave][lane];
        const uint64_t* other = lists[wave ^ 1];
        int cnt = 0;
#pragma unroll
        for (int t = 0; t < KK; ++t) cnt += (other[t] < mine) ? 1 : 0;
        const int rank = lane + cnt;       // keys unique -> exact merged rank
        if (rank < KK) {
            int2 val;
            val.x = b;
            val.y = (int)(uint32_t)(mine & 0xffffffffu);
            *(int2*)(out + (((size_t)q * KK) + (size_t)rank) * 2) = val;
        }
    }
}

extern "C" void kernel_launch(void* const* d_in, const int* in_sizes, int n_in,
                              void* d_out, int out_size, void* d_ws, size_t ws_size,
                              hipStream_t stream) {
    (void)d_ws; (void)ws_size; (void)out_size;
    // setup_inputs order: {'features', 'points'}; pick points by size (2*2048*16).
    const float* points;
    if (n_in >= 2 && in_sizes[1] == 2 * 2048 * 16) {
        points = (const float*)d_in[1];
    } else if (n_in >= 1 && in_sizes[0] == 2 * 2048 * 16) {
        points = (const float*)d_in[0];
    } else {
        points = (const float*)d_in[n_in - 1];
    }
    int* out = (int*)d_out;
    knn_kernel<<<2 * 2048, THREADS, 0, stream>>>(points, out);
}